// Round 1
// baseline (1473.926 us; speedup 1.0000x reference)
//
#include <hip/hip_runtime.h>

// Sinkhorn normalization, N=8192, fp32 in/out.
// Multiplicative-space formulation with fp16 E = exp(s0):
//   v_i = 1 / sum_j E_ij u_j        (row step;  v = e^{-a})
//   u_j = 1 / sum_i E_ij v_i        (col step;  u = e^{-b})
//   out = exp(s0_ij) * v_i * u_j    (final, fp32 exp for precision)
//
// KEY CHANGE vs previous version: the row step and the column-partial step
// are FUSED into a single pass over E. One block per 32-row chunk keeps the
// row batch in registers: dot with u -> block-reduce -> v_i -> accumulate
// v_i*E_ij into per-thread column partials. E streams from HBM once per
// iteration instead of twice (saves ~1.2 GB of 3.4 GB total traffic).
// Partials (8 MB) live in d_out at +128 MB (E occupies the first 128 MB).

constexpr int N = 8192;
constexpr int TB = 1024;                 // threads per fused block
constexpr int CHUNKS = 256;              // one block per CU
constexpr int CHUNK_ROWS = N / CHUNKS;   // 32
constexpr int NH8 = N / 8;               // half8 per row = 1024
constexpr int NV4 = N / 4;               // float4 per row = 2048

typedef _Float16 half8 __attribute__((ext_vector_type(8)));
typedef _Float16 half4 __attribute__((ext_vector_type(4)));

// ---------------------------------------------------------------------------
// Kernel A: E = exp(s0) (fp16), v = 1/rowsum (u == 1 initially), and the
// iteration-0 column partials — all in one pass over s0.
// Thread t owns cols {4t..4t+3} and {4096+4t..4096+4t+3} (fully coalesced
// float4 loads / half4 stores). Batch of 4 rows between barriers.
__global__ __launch_bounds__(TB) void convert_fused(const float* __restrict__ s0,
                                                    _Float16* __restrict__ E,
                                                    float* __restrict__ v,
                                                    float* __restrict__ part) {
    const int t = threadIdx.x;
    const int wave = t >> 6, lane = t & 63;
    const int row0 = blockIdx.x * CHUNK_ROWS;
    const float4* __restrict__ s4 = (const float4*)s0;
    half4* __restrict__ e4 = (half4*)E;
    __shared__ float red[TB / 64][4];
    __shared__ float vv[4];
    float accA[4] = {0.f, 0.f, 0.f, 0.f};
    float accB[4] = {0.f, 0.f, 0.f, 0.f};
    for (int b = 0; b < CHUNK_ROWS; b += 4) {
        float ea[4][4], eb[4][4];
        float d[4];
        #pragma unroll
        for (int r = 0; r < 4; ++r) {
            const int row = row0 + b + r;
            const size_t ro = (size_t)row * NV4;
            float4 xa = s4[ro + t];
            float4 xb = s4[ro + 1024 + t];
            ea[r][0] = __expf(xa.x); ea[r][1] = __expf(xa.y);
            ea[r][2] = __expf(xa.z); ea[r][3] = __expf(xa.w);
            eb[r][0] = __expf(xb.x); eb[r][1] = __expf(xb.y);
            eb[r][2] = __expf(xb.z); eb[r][3] = __expf(xb.w);
            half4 ha, hb;
            #pragma unroll
            for (int k = 0; k < 4; ++k) {
                ha[k] = (_Float16)ea[r][k];
                hb[k] = (_Float16)eb[r][k];
            }
            const size_t rh = (size_t)row * (N / 4);     // half4 stride = 2048
            e4[rh + t] = ha;
            e4[rh + 1024 + t] = hb;
            d[r] = (ea[r][0] + ea[r][1] + ea[r][2] + ea[r][3])
                 + (eb[r][0] + eb[r][1] + eb[r][2] + eb[r][3]);
        }
        #pragma unroll
        for (int off = 32; off > 0; off >>= 1) {
            #pragma unroll
            for (int r = 0; r < 4; ++r) d[r] += __shfl_down(d[r], off, 64);
        }
        if (lane == 0) {
            #pragma unroll
            for (int r = 0; r < 4; ++r) red[wave][r] = d[r];
        }
        __syncthreads();
        if (t < 4) {
            float s = 0.f;
            #pragma unroll
            for (int w = 0; w < TB / 64; ++w) s += red[w][t];
            const float inv = 1.f / s;
            vv[t] = inv;
            v[row0 + b + t] = inv;
        }
        __syncthreads();
        #pragma unroll
        for (int r = 0; r < 4; ++r) {
            const float vr = vv[r];
            #pragma unroll
            for (int k = 0; k < 4; ++k) {
                accA[k] += vr * ea[r][k];
                accB[k] += vr * eb[r][k];
            }
        }
    }
    float4* __restrict__ p4 = (float4*)(part + (size_t)blockIdx.x * N);
    p4[t]        = make_float4(accA[0], accA[1], accA[2], accA[3]);
    p4[1024 + t] = make_float4(accB[0], accB[1], accB[2], accB[3]);
}

// ---------------------------------------------------------------------------
// Kernel B: fused row step + column partials, one pass over E per iteration.
// Thread t owns cols 8t..8t+7 (one half8). Batch of 8 rows between barriers,
// with next-batch prefetch so loads stay in flight across the reduction.
__global__ __launch_bounds__(TB) void fused_pass(const _Float16* __restrict__ E,
                                                 const float* __restrict__ u,
                                                 float* __restrict__ v,
                                                 float* __restrict__ part) {
    const int t = threadIdx.x;
    const int wave = t >> 6, lane = t & 63;
    const int row0 = blockIdx.x * CHUNK_ROWS;
    const half8* __restrict__ e8 = (const half8*)E;
    const float4* __restrict__ u4 = (const float4*)u;
    const float4 ua = u4[2 * t], ub = u4[2 * t + 1];
    __shared__ float red[TB / 64][8];
    __shared__ float vv[8];
    float acc[8] = {0.f, 0.f, 0.f, 0.f, 0.f, 0.f, 0.f, 0.f};
    half8 e[8];
    #pragma unroll
    for (int r = 0; r < 8; ++r)
        e[r] = e8[(size_t)(row0 + r) * NH8 + t];
    #pragma unroll
    for (int b = 0; b < CHUNK_ROWS / 8; ++b) {
        half8 en[8];
        if (b < CHUNK_ROWS / 8 - 1) {
            #pragma unroll
            for (int r = 0; r < 8; ++r)
                en[r] = e8[(size_t)(row0 + (b + 1) * 8 + r) * NH8 + t];
        }
        // row dots with u (v_fma_mix folds the f16->f32 convert into the FMA)
        float d[8];
        #pragma unroll
        for (int r = 0; r < 8; ++r)
            d[r] = ua.x * (float)e[r][0] + ua.y * (float)e[r][1]
                 + ua.z * (float)e[r][2] + ua.w * (float)e[r][3]
                 + ub.x * (float)e[r][4] + ub.y * (float)e[r][5]
                 + ub.z * (float)e[r][6] + ub.w * (float)e[r][7];
        #pragma unroll
        for (int off = 32; off > 0; off >>= 1) {
            #pragma unroll
            for (int r = 0; r < 8; ++r) d[r] += __shfl_down(d[r], off, 64);
        }
        if (lane == 0) {
            #pragma unroll
            for (int r = 0; r < 8; ++r) red[wave][r] = d[r];
        }
        __syncthreads();
        if (t < 8) {
            float s = 0.f;
            #pragma unroll
            for (int w = 0; w < TB / 64; ++w) s += red[w][t];
            const float inv = 1.f / s;
            vv[t] = inv;
            v[row0 + b * 8 + t] = inv;
        }
        __syncthreads();
        #pragma unroll
        for (int r = 0; r < 8; ++r) {
            const float vr = vv[r];
            #pragma unroll
            for (int k = 0; k < 8; ++k)
                acc[k] += vr * (float)e[r][k];
        }
        if (b < CHUNK_ROWS / 8 - 1) {
            #pragma unroll
            for (int r = 0; r < 8; ++r) e[r] = en[r];
        }
    }
    float4* __restrict__ p4 = (float4*)(part + (size_t)blockIdx.x * N);
    p4[2 * t]     = make_float4(acc[0], acc[1], acc[2], acc[3]);
    p4[2 * t + 1] = make_float4(acc[4], acc[5], acc[6], acc[7]);
}

// ---------------------------------------------------------------------------
// u[j] = 1 / sum_c part[c][j].  Grid = N/32 = 256 blocks (full GPU);
// each block does 32 cols, 8-way split over the 256 chunks.
__global__ __launch_bounds__(256) void col_reduce(const float* __restrict__ part,
                                                  float* __restrict__ u) {
    const int c = threadIdx.x & 31;
    const int seg = threadIdx.x >> 5;            // 0..7
    const int col = blockIdx.x * 32 + c;
    float sum = 0.f;
    #pragma unroll 8
    for (int i = 0; i < CHUNKS / 8; ++i)
        sum += part[(size_t)(seg * (CHUNKS / 8) + i) * N + col];
    __shared__ float smem[8][32];
    smem[seg][c] = sum;
    __syncthreads();
    if (threadIdx.x < 32) {
        float s = 0.f;
        #pragma unroll
        for (int q = 0; q < 8; ++q) s += smem[q][threadIdx.x];
        u[blockIdx.x * 32 + threadIdx.x] = 1.f / s;
    }
}

// ---------------------------------------------------------------------------
// out = exp(s0_ij) * v_i * u_j  (fp32 path; overwrites E/part scratch in d_out)
__global__ __launch_bounds__(256) void final_out(const float* __restrict__ s0,
                                                 const float* __restrict__ v,
                                                 const float* __restrict__ u,
                                                 float* __restrict__ out) {
    const int row = blockIdx.x;
    const float vi = v[row];
    const float4* __restrict__ srow = (const float4*)(s0 + (size_t)row * N);
    const float4* __restrict__ u4 = (const float4*)u;
    float4* __restrict__ orow = (float4*)(out + (size_t)row * N);
    for (int k = threadIdx.x; k < NV4; k += 256) {
        float4 x = srow[k];
        float4 uu = u4[k];
        float4 r;
        r.x = __expf(x.x) * vi * uu.x;
        r.y = __expf(x.y) * vi * uu.y;
        r.z = __expf(x.z) * vi * uu.z;
        r.w = __expf(x.w) * vi * uu.w;
        orow[k] = r;
    }
}

extern "C" void kernel_launch(void* const* d_in, const int* in_sizes, int n_in,
                              void* d_out, int out_size, void* d_ws, size_t ws_size,
                              hipStream_t stream) {
    const float* s0 = (const float*)d_in[0];
    float* out = (float*)d_out;

    _Float16* E = (_Float16*)d_out;                                  // 128 MB scratch
    float* part = (float*)((char*)d_out + (size_t)N * N * 2);        // 8 MB at +128 MB
    float* v = (float*)d_ws;                                         // 8192 floats
    float* u = v + N;                                                // 8192 floats

    convert_fused<<<CHUNKS, TB, 0, stream>>>(s0, E, v, part);        // row step #1 (u==1) + col partials
    col_reduce<<<N / 32, 256, 0, stream>>>(part, u);                 // col step #1
    for (int it = 1; it < 10; ++it) {
        fused_pass<<<CHUNKS, TB, 0, stream>>>(E, u, v, part);        // row step + col partials
        col_reduce<<<N / 32, 256, 0, stream>>>(part, u);             // col step
    }
    final_out<<<N, 256, 0, stream>>>(s0, v, u, out);
}